// Round 3
// baseline (354.536 us; speedup 1.0000x reference)
//
#include <hip/hip_runtime.h>

// Problem constants
#define S_LEN 256
#define B_SZ  128
#define M_ROWS (S_LEN * B_SZ)          // 32768

typedef __attribute__((ext_vector_type(8))) short bf16x8;
typedef __attribute__((ext_vector_type(4))) float f32x4;

__device__ __forceinline__ unsigned short f2bf(float x) {
    unsigned u = __float_as_uint(x);
    unsigned r = (u + 0x7fffu + ((u >> 16) & 1u)) >> 16;   // RNE
    return (unsigned short)r;
}

__device__ __forceinline__ void gl_lds16(const void* g, void* l) {
    __builtin_amdgcn_global_load_lds(
        (const __attribute__((address_space(1))) unsigned int*)g,
        (__attribute__((address_space(3))) unsigned int*)l,
        16, 0, 0);
}

// ---------------- Pass 1: seq f32 -> bf16 ----------------
__global__ __launch_bounds__(256) void convert_seq(const float* __restrict__ in,
                                                   unsigned short* __restrict__ out,
                                                   long n4) {
    long i = (long)blockIdx.x * blockDim.x + threadIdx.x;
    long stride = (long)gridDim.x * blockDim.x;
    for (; i < n4; i += stride) {
        float4 v = ((const float4*)in)[i];
        ushort4 o;
        o.x = f2bf(v.x); o.y = f2bf(v.y); o.z = f2bf(v.z); o.w = f2bf(v.w);
        ((ushort4*)out)[i] = o;
    }
}

// ---------------- Pass 2: f1,f2 f32 -> bf16 (layer-major) ----------------
__global__ __launch_bounds__(256) void convert_f(const float* __restrict__ f1,
                                                 const float* __restrict__ f2,
                                                 unsigned short* __restrict__ out) {
    int g = blockIdx.x * 256 + threadIdx.x;            // 0..65535 float4 groups
    float4 v = (g < 32768) ? ((const float4*)f1)[g] : ((const float4*)f2)[g - 32768];
    ushort4 o;
    o.x = f2bf(v.x); o.y = f2bf(v.y); o.z = f2bf(v.z); o.w = f2bf(v.w);
    ((ushort4*)out)[g] = o;
}

// ---------------- Pass 3: W [2048][1024] f32 -> Wt [2][1024][2048] bf16 ----------------
__global__ __launch_bounds__(256) void transpose_w(const float* __restrict__ W11,
                                                   const float* __restrict__ W12,
                                                   unsigned short* __restrict__ Wt) {
    const int nt = blockIdx.x, kt = blockIdx.y, layer = blockIdx.z;
    const float* W = layer ? W12 : W11;
    __shared__ float T[64][65];
    const int c = threadIdx.x & 63, r4 = threadIdx.x >> 6;
    const int k0 = kt * 64, n0 = nt * 64;
    #pragma unroll
    for (int p = 0; p < 16; ++p) {
        int r = p * 4 + r4;
        T[r][c] = W[(size_t)(k0 + r) * 1024 + n0 + c];
    }
    __syncthreads();
    unsigned short* Wl = Wt + (size_t)layer * 1024 * 2048;
    #pragma unroll
    for (int p = 0; p < 16; ++p) {
        int n = p * 4 + r4;
        Wl[(size_t)(n0 + n) * 2048 + k0 + c] = f2bf(T[c][n]);
    }
}

// ---------------- Pass 4: c[layer][b][h] = f@W[1024:] + bias  (MFMA 128x128 tile) ----------------
__global__ __launch_bounds__(256) void c_precompute(const unsigned short* __restrict__ fbf, // [2][128][1024]
                                                    const unsigned short* __restrict__ Wt,  // [2][1024][2048]
                                                    const float* __restrict__ b11,
                                                    const float* __restrict__ b12,
                                                    float* __restrict__ cbuf) {            // [2][128][1024]
    __shared__ char smem[32768];
    unsigned short* ldsA = (unsigned short*)smem;            // [128][64]
    unsigned short* ldsB = (unsigned short*)(smem + 16384);  // [128][64]
    const int n0 = blockIdx.x * 128;
    const int layer = blockIdx.y;
    const int tid = threadIdx.x;
    const int w = tid >> 6, l = tid & 63;
    const int wm = w >> 1, wn = w & 1;
    const int lr = l & 15, lg = l >> 4;
    const unsigned short* Af = fbf + (size_t)layer * 128 * 1024;
    const unsigned short* Wl = Wt + (size_t)layer * 1024 * 2048;
    const float* bias = layer ? b12 : b11;

    f32x4 acc[4][4];
    #pragma unroll
    for (int i = 0; i < 4; ++i)
        #pragma unroll
        for (int j = 0; j < 4; ++j)
            #pragma unroll
            for (int e = 0; e < 4; ++e) acc[i][j][e] = 0.f;

    for (int kk = 0; kk < 1024; kk += 64) {
        __syncthreads();
        #pragma unroll
        for (int c = 0; c < 4; ++c) {
            int o = w * 4096 + c * 1024;
            int ob = o + l * 16;
            int row = ob >> 7, kb = ob & 127;
            gl_lds16((const char*)Af + ((size_t)row * 1024 + kk) * 2 + kb, (char*)ldsA + o);
            gl_lds16((const char*)Wl + ((size_t)(n0 + row) * 2048 + 1024 + kk) * 2 + kb, (char*)ldsB + o);
        }
        __syncthreads();
        #pragma unroll
        for (int ks = 0; ks < 2; ++ks) {
            bf16x8 av[4], bv[4];
            #pragma unroll
            for (int i = 0; i < 4; ++i) {
                av[i] = *(const bf16x8*)(ldsA + (wm * 64 + i * 16 + lr) * 64 + ks * 32 + lg * 8);
                bv[i] = *(const bf16x8*)(ldsB + (wn * 64 + i * 16 + lr) * 64 + ks * 32 + lg * 8);
            }
            #pragma unroll
            for (int i = 0; i < 4; ++i)
                #pragma unroll
                for (int j = 0; j < 4; ++j)
                    acc[i][j] = __builtin_amdgcn_mfma_f32_16x16x32_bf16(av[i], bv[j], acc[i][j], 0, 0, 0);
        }
    }
    float* cl = cbuf + (size_t)layer * 128 * 1024;
    #pragma unroll
    for (int i = 0; i < 4; ++i)
        #pragma unroll
        for (int j = 0; j < 4; ++j)
            #pragma unroll
            for (int q = 0; q < 4; ++q) {
                int rr = wm * 64 + i * 16 + lg * 4 + q;
                int hc = n0 + wn * 64 + j * 16 + lr;
                cl[(size_t)rr * 1024 + hc] = acc[i][j][q] + bias[hc];
            }
}

// ================= Pass 5: main fused GEMM, 256x256 tile, 8-phase schedule =================
// Half-tile LDS layout: [128][64] bf16 (16 KB), st_16x32 swizzle: byte ^= ((byte>>9)&1)<<5.
// Staged via global_load_lds with LINEAR dest + inverse-swizzled global source (involution).

__device__ __forceinline__ bf16x8 ldsw(const char* buf, int row, int colb) {
    int lb = row * 128 + colb;
    lb ^= ((lb >> 9) & 1) << 5;
    return *(const bf16x8*)(buf + lb);
}

template<int STRIDE>
__device__ __forceinline__ void stage_half(const char* gsrc, char* ldsbuf, int w, int l) {
    #pragma unroll
    for (int c = 0; c < 2; ++c) {
        int dloc = (w * 2 + c) * 1024 + l * 16;
        int g = dloc ^ (((dloc >> 9) & 1) << 5);
        gl_lds16(gsrc + (size_t)(g >> 7) * STRIDE + (g & 127), ldsbuf + (w * 2 + c) * 1024);
    }
}

template<int IB>
__device__ __forceinline__ void read_av(bf16x8* av, const char* buf, int lr, int lg) {
    #pragma unroll
    for (int i = 0; i < 4; ++i)
        #pragma unroll
        for (int ks = 0; ks < 2; ++ks)
            av[i * 2 + ks] = ldsw(buf, (IB + i) * 16 + lr, ks * 64 + lg * 16);
}

template<int JB>
__device__ __forceinline__ void read_bv(bf16x8* bv, const char* buf, int br, int lr, int lg) {
    #pragma unroll
    for (int j = 0; j < 2; ++j)
        #pragma unroll
        for (int ks = 0; ks < 2; ++ks)
            bv[j * 2 + ks] = ldsw(buf, br + (JB + j) * 16 + lr, ks * 64 + lg * 16);
}

template<int IB, int JB>
__device__ __forceinline__ void mfma_quad(f32x4 (&acc)[8][4], const bf16x8* av, const bf16x8* bv) {
    #pragma unroll
    for (int i = 0; i < 4; ++i)
        #pragma unroll
        for (int j = 0; j < 2; ++j)
            #pragma unroll
            for (int ks = 0; ks < 2; ++ks)
                acc[IB + i][JB + j] = __builtin_amdgcn_mfma_f32_16x16x32_bf16(
                    av[i * 2 + ks], bv[j * 2 + ks], acc[IB + i][JB + j], 0, 0, 0);
}

__device__ __forceinline__ void phase_mid() {
    __builtin_amdgcn_sched_barrier(0);
    __builtin_amdgcn_s_barrier();
    asm volatile("s_waitcnt lgkmcnt(0)" ::: "memory");
    __builtin_amdgcn_sched_barrier(0);
    __builtin_amdgcn_s_setprio(1);
}
__device__ __forceinline__ void phase_end() {
    __builtin_amdgcn_s_setprio(0);
    __builtin_amdgcn_sched_barrier(0);
    __builtin_amdgcn_s_barrier();
}

__global__ __launch_bounds__(512) void fused_main(const unsigned short* __restrict__ Abf, // [32768][1024] bf16
                                                  const unsigned short* __restrict__ Wt,  // [2][1024][2048] bf16
                                                  const float* __restrict__ cbuf,         // [2][128][1024]
                                                  const float* __restrict__ W21,
                                                  const float* __restrict__ W22,
                                                  float* __restrict__ sbufp) {            // [8][32768]
    __shared__ char smem[131072];
    const int layer = blockIdx.x >> 2;
    const int nt    = blockIdx.x & 3;
    const int bx    = blockIdx.y;                  // M-tile (256 rows)
    const int tid = threadIdx.x;
    const int w = tid >> 6, l = tid & 63;
    const int wm = w >> 2, wn = w & 3;             // 2 M-halves x 4 N-quarters
    const int lr = l & 15, lg = l >> 4;
    const int bh = wn >> 1, br = (wn & 1) * 64;    // B half-buffer + row base within it
    const int n0 = nt * 256;

    const char* Ag = (const char*)Abf + (size_t)bx * 256 * 2048;                    // row stride 2048 B
    const char* Bg = (const char*)(Wt + (size_t)layer * 1024 * 2048) + (size_t)n0 * 4096; // row stride 4096 B

    char* A0 = smem;              // dbuf0 A halves @ 0, 16384
    char* B0 = smem + 32768;      // dbuf0 B halves
    char* A1 = smem + 65536;      // dbuf1 A halves
    char* B1 = smem + 98304;      // dbuf1 B halves

    f32x4 acc[8][4];
    #pragma unroll
    for (int i = 0; i < 8; ++i)
        #pragma unroll
        for (int j = 0; j < 4; ++j)
            #pragma unroll
            for (int e = 0; e < 4; ++e) acc[i][j][e] = 0.f;

    // ---- prologue: K-tile0 -> dbuf0 (B,A), K-tile1 B -> dbuf1 ----
    stage_half<4096>(Bg,                  B0,         w, l);
    stage_half<4096>(Bg + 524288,         B0 + 16384, w, l);
    stage_half<2048>(Ag,                  A0,         w, l);
    stage_half<2048>(Ag + 262144,         A0 + 16384, w, l);
    stage_half<4096>(Bg + 128,            B1,         w, l);
    stage_half<4096>(Bg + 524288 + 128,   B1 + 16384, w, l);
    asm volatile("s_waitcnt vmcnt(4)" ::: "memory");
    __builtin_amdgcn_sched_barrier(0);
    __builtin_amdgcn_s_barrier();

    const char* Awm0 = A0 + wm * 16384;
    const char* Awm1 = A1 + wm * 16384;
    const char* Bb0  = B0 + bh * 16384;
    const char* Bb1  = B1 + bh * 16384;

    bf16x8 av[8], bvl[4], bvh[4];

    for (int r = 0; r < 8; ++r) {
        const size_t t1 = (size_t)(2 * r + 1) * 128;
        const int   c2 = 2 * r + 2 < 16 ? 2 * r + 2 : 15;
        const int   c3 = 2 * r + 3 < 16 ? 2 * r + 3 : 15;
        const size_t t2 = (size_t)c2 * 128;
        const size_t t3 = (size_t)c3 * 128;

        // ph1: dbuf0 av_lo+bv_lo reads | stage A1h0(2r+1) | MFMA Q0
        read_av<0>(av, Awm0, lr, lg);
        read_bv<0>(bvl, Bb0, br, lr, lg);
        stage_half<2048>(Ag + t1, A1, w, l);
        phase_mid(); mfma_quad<0, 0>(acc, av, bvl); phase_end();

        // ph2: bv_hi | stage A1h1(2r+1) | Q1
        read_bv<2>(bvh, Bb0, br, lr, lg);
        stage_half<2048>(Ag + 262144 + t1, A1 + 16384, w, l);
        phase_mid(); mfma_quad<0, 2>(acc, av, bvh); phase_end();

        // ph3: av_hi | stage B0h0(2r+2) | Q2
        read_av<4>(av, Awm0, lr, lg);
        stage_half<4096>(Bg + t2, B0, w, l);
        phase_mid(); mfma_quad<4, 0>(acc, av, bvl); phase_end();

        // ph4: stage B0h1(2r+2) | vmcnt(4) | Q3
        stage_half<4096>(Bg + 524288 + t2, B0 + 16384, w, l);
        asm volatile("s_waitcnt vmcnt(4)" ::: "memory");
        phase_mid(); mfma_quad<4, 2>(acc, av, bvh); phase_end();

        // ph5: dbuf1 av_lo+bv_lo | stage A0h0(2r+2) | Q0
        read_av<0>(av, Awm1, lr, lg);
        read_bv<0>(bvl, Bb1, br, lr, lg);
        stage_half<2048>(Ag + t2, A0, w, l);
        phase_mid(); mfma_quad<0, 0>(acc, av, bvl); phase_end();

        // ph6: bv_hi | stage A0h1(2r+2) | Q1
        read_bv<2>(bvh, Bb1, br, lr, lg);
        stage_half<2048>(Ag + 262144 + t2, A0 + 16384, w, l);
        phase_mid(); mfma_quad<0, 2>(acc, av, bvh); phase_end();

        // ph7: av_hi | stage B1h0(2r+3) | Q2
        read_av<4>(av, Awm1, lr, lg);
        stage_half<4096>(Bg + t3, B1, w, l);
        phase_mid(); mfma_quad<4, 0>(acc, av, bvl); phase_end();

        // ph8: stage B1h1(2r+3) | vmcnt(4) | Q3
        stage_half<4096>(Bg + 524288 + t3, B1 + 16384, w, l);
        asm volatile("s_waitcnt vmcnt(4)" ::: "memory");
        phase_mid(); mfma_quad<4, 2>(acc, av, bvh); phase_end();
    }

    asm volatile("s_waitcnt vmcnt(0) lgkmcnt(0)" ::: "memory");
    __syncthreads();

    // ---- epilogue: z = acc + c, h = tanh(z), dot with W21/W22, reduce ----
    const float* cl = cbuf + (size_t)layer * 131072;
    const float* W2 = layer ? W22 : W21;
    float w2v[4];
    #pragma unroll
    for (int j = 0; j < 4; ++j) w2v[j] = W2[n0 + wn * 64 + j * 16 + lr];
    float* red = (float*)smem;   // [256][4]
    #pragma unroll
    for (int i = 0; i < 8; ++i) {
        #pragma unroll
        for (int q = 0; q < 4; ++q) {
            int wrow = wm * 128 + i * 16 + lg * 4 + q;   // 0..255 within M-tile
            int brow = wrow & 127;                        // b index (bx*256 ≡ 0 mod 128)
            float p = 0.f;
            #pragma unroll
            for (int j = 0; j < 4; ++j) {
                int col = n0 + wn * 64 + j * 16 + lr;
                float z = acc[i][j][q] + cl[(size_t)brow * 1024 + col];
                float e = __expf(2.f * z);
                p += (1.f - 2.f / (e + 1.f)) * w2v[j];
            }
            p += __shfl_xor(p, 1);
            p += __shfl_xor(p, 2);
            p += __shfl_xor(p, 4);
            p += __shfl_xor(p, 8);
            if (lr == 0) red[wrow * 4 + wn] = p;
        }
    }
    __syncthreads();
    if (tid < 256) {
        float v = red[tid * 4 + 0] + red[tid * 4 + 1] + red[tid * 4 + 2] + red[tid * 4 + 3];
        sbufp[(size_t)blockIdx.x * M_ROWS + (size_t)bx * 256 + tid] = v;
    }
}

// ---------------- Pass 6: softmax over s -> coef; also zero d_out ----------------
__device__ __forceinline__ float block_max(float v, float* lds) {
    #pragma unroll
    for (int m = 32; m; m >>= 1) v = fmaxf(v, __shfl_xor(v, m));
    if ((threadIdx.x & 63) == 0) lds[threadIdx.x >> 6] = v;
    __syncthreads();
    v = fmaxf(fmaxf(lds[0], lds[1]), fmaxf(lds[2], lds[3]));
    __syncthreads();
    return v;
}
__device__ __forceinline__ float block_sum(float v, float* lds) {
    #pragma unroll
    for (int m = 32; m; m >>= 1) v += __shfl_xor(v, m);
    if ((threadIdx.x & 63) == 0) lds[threadIdx.x >> 6] = v;
    __syncthreads();
    v = lds[0] + lds[1] + lds[2] + lds[3];
    __syncthreads();
    return v;
}

__global__ __launch_bounds__(256) void coef_kernel(const float* __restrict__ sbufp,
                                                   float* __restrict__ coef,
                                                   float* __restrict__ out) {
    __shared__ float lds[4];
    const int b = blockIdx.x, s = threadIdx.x;
    float v1 = 0.f, v2 = 0.f;
    #pragma unroll
    for (int nt = 0; nt < 4; ++nt) {
        v1 += sbufp[(size_t)nt * M_ROWS + (size_t)s * 128 + b];
        v2 += sbufp[(size_t)(4 + nt) * M_ROWS + (size_t)s * 128 + b];
    }
    float m1 = block_max(v1, lds);
    float e1 = expf(v1 - m1);
    float S1 = block_sum(e1, lds);
    float m2 = block_max(v2, lds);
    float e2 = expf(v2 - m2);
    float S2 = block_sum(e2, lds);
    coef[(size_t)s * 128 + b] = (e1 / S1 + e2 / S2) * (0.5f / (float)S_LEN);
    // zero d_out: block b owns row b (1024 floats = 256 float4)
    float4 z4; z4.x = z4.y = z4.z = z4.w = 0.f;
    ((float4*)out)[(size_t)b * 256 + s] = z4;
}

// ---------------- Pass 7: out[b][d] = sum_s coef[s][b] * seq[s][b][d] ----------------
__global__ __launch_bounds__(256) void final_kernel(const float* __restrict__ seq,
                                                    const float* __restrict__ coef,
                                                    float* __restrict__ out) {
    const int b = blockIdx.x, q = blockIdx.y;
    const int d0 = threadIdx.x * 4;
    float4 a; a.x = a.y = a.z = a.w = 0.f;
    for (int si = 0; si < 32; ++si) {
        int s = q * 32 + si;
        float cf = coef[(size_t)s * 128 + b];
        float4 v = *(const float4*)(seq + ((size_t)(s * 128 + b) * 1024 + d0));
        a.x += cf * v.x; a.y += cf * v.y; a.z += cf * v.z; a.w += cf * v.w;
    }
    float* o = out + (size_t)b * 1024 + d0;
    atomicAdd(o + 0, a.x);
    atomicAdd(o + 1, a.y);
    atomicAdd(o + 2, a.z);
    atomicAdd(o + 3, a.w);
}

extern "C" void kernel_launch(void* const* d_in, const int* in_sizes, int n_in,
                              void* d_out, int out_size, void* d_ws, size_t ws_size,
                              hipStream_t stream) {
    const float* feature1 = (const float*)d_in[0];   // [128,1024]
    const float* feature2 = (const float*)d_in[1];   // [128,1024]
    const float* seq      = (const float*)d_in[2];   // [256,128,1024]
    const float* W11      = (const float*)d_in[3];   // [2048,1024]
    const float* b11      = (const float*)d_in[4];
    const float* W12      = (const float*)d_in[5];
    const float* b12      = (const float*)d_in[6];
    const float* W21      = (const float*)d_in[7];   // [1024,1]
    const float* W22      = (const float*)d_in[9];
    float* out = (float*)d_out;

    char* ws = (char*)d_ws;
    unsigned short* Abf   = (unsigned short*)(ws + 0);                  // 67108864 B
    unsigned short* Wt    = (unsigned short*)(ws + 67108864);           //  8388608 B
    unsigned short* fbf   = (unsigned short*)(ws + 75497472);           //   524288 B
    float*          cbuf  = (float*)(ws + 76021760);                    //  1048576 B
    float*          sbufp = (float*)(ws + 77070336);                    //  1048576 B  [8][32768]
    float*          coef  = (float*)(ws + 78118912);                    //   131072 B

    convert_seq<<<2048, 256, 0, stream>>>(seq, Abf, (long)M_ROWS * 1024 / 4);
    convert_f<<<256, 256, 0, stream>>>(feature1, feature2, fbf);
    transpose_w<<<dim3(16, 32, 2), 256, 0, stream>>>(W11, W12, Wt);
    c_precompute<<<dim3(8, 2), 256, 0, stream>>>(fbf, Wt, b11, b12, cbuf);
    fused_main<<<dim3(8, 128), 512, 0, stream>>>(Abf, Wt, cbuf, W21, W22, sbufp);
    coef_kernel<<<128, 256, 0, stream>>>(sbufp, coef, out);
    final_kernel<<<dim3(128, 8), 256, 0, stream>>>(seq, coef, out);
}

// Round 4
// 271.567 us; speedup vs baseline: 1.3055x; 1.3055x over previous
//
#include <hip/hip_runtime.h>

// Problem constants
#define S_LEN 256
#define B_SZ  128
#define M_ROWS (S_LEN * B_SZ)          // 32768

typedef __attribute__((ext_vector_type(8))) short bf16x8;
typedef __attribute__((ext_vector_type(4))) float f32x4;

__device__ __forceinline__ unsigned short f2bf(float x) {
    unsigned u = __float_as_uint(x);
    unsigned r = (u + 0x7fffu + ((u >> 16) & 1u)) >> 16;   // RNE
    return (unsigned short)r;
}

__device__ __forceinline__ void gl_lds16(const void* g, void* l) {
    __builtin_amdgcn_global_load_lds(
        (const __attribute__((address_space(1))) unsigned int*)g,
        (__attribute__((address_space(3))) unsigned int*)l,
        16, 0, 0);
}

// ---------------- Pass 1: seq f32 -> bf16 ----------------
__global__ __launch_bounds__(256) void convert_seq(const float* __restrict__ in,
                                                   unsigned short* __restrict__ out,
                                                   long n4) {
    long i = (long)blockIdx.x * blockDim.x + threadIdx.x;
    long stride = (long)gridDim.x * blockDim.x;
    for (; i < n4; i += stride) {
        float4 v = ((const float4*)in)[i];
        ushort4 o;
        o.x = f2bf(v.x); o.y = f2bf(v.y); o.z = f2bf(v.z); o.w = f2bf(v.w);
        ((ushort4*)out)[i] = o;
    }
}

// ---------------- Pass 2: f1,f2 f32 -> bf16 (layer-major) ----------------
__global__ __launch_bounds__(256) void convert_f(const float* __restrict__ f1,
                                                 const float* __restrict__ f2,
                                                 unsigned short* __restrict__ out) {
    int g = blockIdx.x * 256 + threadIdx.x;            // 0..65535 float4 groups
    float4 v = (g < 32768) ? ((const float4*)f1)[g] : ((const float4*)f2)[g - 32768];
    ushort4 o;
    o.x = f2bf(v.x); o.y = f2bf(v.y); o.z = f2bf(v.z); o.w = f2bf(v.w);
    ((ushort4*)out)[g] = o;
}

// ---------------- Pass 3: W [2048][1024] f32 -> Wt [2][1024][2048] bf16 ----------------
__global__ __launch_bounds__(256) void transpose_w(const float* __restrict__ W11,
                                                   const float* __restrict__ W12,
                                                   unsigned short* __restrict__ Wt) {
    const int nt = blockIdx.x, kt = blockIdx.y, layer = blockIdx.z;
    const float* W = layer ? W12 : W11;
    __shared__ float T[64][65];
    const int c = threadIdx.x & 63, r4 = threadIdx.x >> 6;
    const int k0 = kt * 64, n0 = nt * 64;
    #pragma unroll
    for (int p = 0; p < 16; ++p) {
        int r = p * 4 + r4;
        T[r][c] = W[(size_t)(k0 + r) * 1024 + n0 + c];
    }
    __syncthreads();
    unsigned short* Wl = Wt + (size_t)layer * 1024 * 2048;
    #pragma unroll
    for (int p = 0; p < 16; ++p) {
        int n = p * 4 + r4;
        Wl[(size_t)(n0 + n) * 2048 + k0 + c] = f2bf(T[c][n]);
    }
}

// ---------------- Pass 4: c[layer][b][h] = f@W[1024:] + bias  (MFMA 128x128 tile) ----------------
__global__ __launch_bounds__(256) void c_precompute(const unsigned short* __restrict__ fbf, // [2][128][1024]
                                                    const unsigned short* __restrict__ Wt,  // [2][1024][2048]
                                                    const float* __restrict__ b11,
                                                    const float* __restrict__ b12,
                                                    float* __restrict__ cbuf) {            // [2][128][1024]
    __shared__ char smem[32768];
    unsigned short* ldsA = (unsigned short*)smem;            // [128][64]
    unsigned short* ldsB = (unsigned short*)(smem + 16384);  // [128][64]
    const int n0 = blockIdx.x * 128;
    const int layer = blockIdx.y;
    const int tid = threadIdx.x;
    const int w = tid >> 6, l = tid & 63;
    const int wm = w >> 1, wn = w & 1;
    const int lr = l & 15, lg = l >> 4;
    const unsigned short* Af = fbf + (size_t)layer * 128 * 1024;
    const unsigned short* Wl = Wt + (size_t)layer * 1024 * 2048;
    const float* bias = layer ? b12 : b11;

    f32x4 acc[4][4];
    #pragma unroll
    for (int i = 0; i < 4; ++i)
        #pragma unroll
        for (int j = 0; j < 4; ++j)
            #pragma unroll
            for (int e = 0; e < 4; ++e) acc[i][j][e] = 0.f;

    for (int kk = 0; kk < 1024; kk += 64) {
        __syncthreads();
        #pragma unroll
        for (int c = 0; c < 4; ++c) {
            int o = w * 4096 + c * 1024;
            int ob = o + l * 16;
            int row = ob >> 7, kb = ob & 127;
            gl_lds16((const char*)Af + ((size_t)row * 1024 + kk) * 2 + kb, (char*)ldsA + o);
            gl_lds16((const char*)Wl + ((size_t)(n0 + row) * 2048 + 1024 + kk) * 2 + kb, (char*)ldsB + o);
        }
        __syncthreads();
        #pragma unroll
        for (int ks = 0; ks < 2; ++ks) {
            bf16x8 av[4], bv[4];
            #pragma unroll
            for (int i = 0; i < 4; ++i) {
                av[i] = *(const bf16x8*)(ldsA + (wm * 64 + i * 16 + lr) * 64 + ks * 32 + lg * 8);
                bv[i] = *(const bf16x8*)(ldsB + (wn * 64 + i * 16 + lr) * 64 + ks * 32 + lg * 8);
            }
            #pragma unroll
            for (int i = 0; i < 4; ++i)
                #pragma unroll
                for (int j = 0; j < 4; ++j)
                    acc[i][j] = __builtin_amdgcn_mfma_f32_16x16x32_bf16(av[i], bv[j], acc[i][j], 0, 0, 0);
        }
    }
    float* cl = cbuf + (size_t)layer * 128 * 1024;
    #pragma unroll
    for (int i = 0; i < 4; ++i)
        #pragma unroll
        for (int j = 0; j < 4; ++j)
            #pragma unroll
            for (int q = 0; q < 4; ++q) {
                int rr = wm * 64 + i * 16 + lg * 4 + q;
                int hc = n0 + wn * 64 + j * 16 + lr;
                cl[(size_t)rr * 1024 + hc] = acc[i][j][q] + bias[hc];
            }
}

// ================= Pass 5: main fused GEMM, 256x256 tile, 8-phase schedule =================
// Half-tile LDS layout: [128 rows][128 B] bf16 (16 KB).
// Swizzle (involution on byte addr): x ^= ((x>>3) & 0x70)  — XOR row&7 (bits 7-9)
// into the 16B-slot index (bits 4-6). A wave's 16 lr-rows then cover all 8 slots
// of a 128B row => 2 lanes/bank = conflict-free (G4 derivation, m136).
// Staged via global_load_lds with LINEAR dest + inverse-swizzled global source.

__device__ __forceinline__ bf16x8 ldsw(const char* buf, int row, int colb) {
    int lb = row * 128 + (colb ^ ((row & 7) << 4));
    return *(const bf16x8*)(buf + lb);
}

template<int STRIDE>
__device__ __forceinline__ void stage_half(const char* gsrc, char* ldsbuf, int w, int l) {
    #pragma unroll
    for (int c = 0; c < 2; ++c) {
        int dloc = (w * 2 + c) * 1024 + l * 16;
        int g = dloc ^ ((dloc >> 3) & 0x70);
        gl_lds16(gsrc + (size_t)(g >> 7) * STRIDE + (g & 127), ldsbuf + (w * 2 + c) * 1024);
    }
}

template<int IB>
__device__ __forceinline__ void read_av(bf16x8* av, const char* buf, int lr, int lg) {
    #pragma unroll
    for (int i = 0; i < 4; ++i)
        #pragma unroll
        for (int ks = 0; ks < 2; ++ks)
            av[i * 2 + ks] = ldsw(buf, (IB + i) * 16 + lr, ks * 64 + lg * 16);
}

template<int JB>
__device__ __forceinline__ void read_bv(bf16x8* bv, const char* buf, int br, int lr, int lg) {
    #pragma unroll
    for (int j = 0; j < 2; ++j)
        #pragma unroll
        for (int ks = 0; ks < 2; ++ks)
            bv[j * 2 + ks] = ldsw(buf, br + (JB + j) * 16 + lr, ks * 64 + lg * 16);
}

template<int IB, int JB>
__device__ __forceinline__ void mfma_quad(f32x4 (&acc)[8][4], const bf16x8* av, const bf16x8* bv) {
    #pragma unroll
    for (int i = 0; i < 4; ++i)
        #pragma unroll
        for (int j = 0; j < 2; ++j)
            #pragma unroll
            for (int ks = 0; ks < 2; ++ks)
                acc[IB + i][JB + j] = __builtin_amdgcn_mfma_f32_16x16x32_bf16(
                    av[i * 2 + ks], bv[j * 2 + ks], acc[IB + i][JB + j], 0, 0, 0);
}

__device__ __forceinline__ void phase_mid() {
    __builtin_amdgcn_sched_barrier(0);
    __builtin_amdgcn_s_barrier();
    asm volatile("s_waitcnt lgkmcnt(0)" ::: "memory");
    __builtin_amdgcn_sched_barrier(0);
    __builtin_amdgcn_s_setprio(1);
}
__device__ __forceinline__ void phase_end() {
    __builtin_amdgcn_s_setprio(0);
    __builtin_amdgcn_sched_barrier(0);
    __builtin_amdgcn_s_barrier();
}

__global__ __launch_bounds__(512) void fused_main(const unsigned short* __restrict__ Abf, // [32768][1024] bf16
                                                  const unsigned short* __restrict__ Wt,  // [2][1024][2048] bf16
                                                  const float* __restrict__ cbuf,         // [2][128][1024]
                                                  const float* __restrict__ W21,
                                                  const float* __restrict__ W22,
                                                  float* __restrict__ sbufp) {            // [8][32768]
    __shared__ char smem[131072];
    const int layer = blockIdx.x >> 2;
    const int nt    = blockIdx.x & 3;
    const int bx    = blockIdx.y;                  // M-tile (256 rows)
    const int tid = threadIdx.x;
    const int w = tid >> 6, l = tid & 63;
    const int wm = w >> 2, wn = w & 3;             // 2 M-halves x 4 N-quarters
    const int lr = l & 15, lg = l >> 4;
    const int bh = wn >> 1, br = (wn & 1) * 64;    // B half-buffer + row base within it
    const int n0 = nt * 256;

    const char* Ag = (const char*)Abf + (size_t)bx * 256 * 2048;                    // row stride 2048 B
    const char* Bg = (const char*)(Wt + (size_t)layer * 1024 * 2048) + (size_t)n0 * 4096; // row stride 4096 B

    char* A0 = smem;              // dbuf0 A halves @ 0, 16384
    char* B0 = smem + 32768;      // dbuf0 B halves
    char* A1 = smem + 65536;      // dbuf1 A halves
    char* B1 = smem + 98304;      // dbuf1 B halves

    f32x4 acc[8][4];
    #pragma unroll
    for (int i = 0; i < 8; ++i)
        #pragma unroll
        for (int j = 0; j < 4; ++j)
            #pragma unroll
            for (int e = 0; e < 4; ++e) acc[i][j][e] = 0.f;

    // ---- prologue: K-tile0 -> dbuf0 (B,A), K-tile1 B -> dbuf1 ----
    stage_half<4096>(Bg,                  B0,         w, l);
    stage_half<4096>(Bg + 524288,         B0 + 16384, w, l);
    stage_half<2048>(Ag,                  A0,         w, l);
    stage_half<2048>(Ag + 262144,         A0 + 16384, w, l);
    stage_half<4096>(Bg + 128,            B1,         w, l);
    stage_half<4096>(Bg + 524288 + 128,   B1 + 16384, w, l);
    asm volatile("s_waitcnt vmcnt(4)" ::: "memory");
    __builtin_amdgcn_sched_barrier(0);
    __builtin_amdgcn_s_barrier();

    const char* Awm0 = A0 + wm * 16384;
    const char* Awm1 = A1 + wm * 16384;
    const char* Bb0  = B0 + bh * 16384;
    const char* Bb1  = B1 + bh * 16384;

    bf16x8 av[8], bvl[4], bvh[4];

    for (int r = 0; r < 8; ++r) {
        const size_t t1 = (size_t)(2 * r + 1) * 128;
        const int   c2 = 2 * r + 2 < 16 ? 2 * r + 2 : 15;
        const int   c3 = 2 * r + 3 < 16 ? 2 * r + 3 : 15;
        const size_t t2 = (size_t)c2 * 128;
        const size_t t3 = (size_t)c3 * 128;

        // ph1: dbuf0 av_lo+bv_lo reads | stage A1h0(2r+1) | MFMA Q0
        read_av<0>(av, Awm0, lr, lg);
        read_bv<0>(bvl, Bb0, br, lr, lg);
        stage_half<2048>(Ag + t1, A1, w, l);
        phase_mid(); mfma_quad<0, 0>(acc, av, bvl); phase_end();

        // ph2: bv_hi | stage A1h1(2r+1) | Q1
        read_bv<2>(bvh, Bb0, br, lr, lg);
        stage_half<2048>(Ag + 262144 + t1, A1 + 16384, w, l);
        phase_mid(); mfma_quad<0, 2>(acc, av, bvh); phase_end();

        // ph3: av_hi | stage B0h0(2r+2) | Q2
        read_av<4>(av, Awm0, lr, lg);
        stage_half<4096>(Bg + t2, B0, w, l);
        phase_mid(); mfma_quad<4, 0>(acc, av, bvl); phase_end();

        // ph4: stage B0h1(2r+2) | vmcnt(4) | Q3
        stage_half<4096>(Bg + 524288 + t2, B0 + 16384, w, l);
        asm volatile("s_waitcnt vmcnt(4)" ::: "memory");
        phase_mid(); mfma_quad<4, 2>(acc, av, bvh); phase_end();

        // ph5: dbuf1 av_lo+bv_lo | stage A0h0(2r+2) | Q0
        read_av<0>(av, Awm1, lr, lg);
        read_bv<0>(bvl, Bb1, br, lr, lg);
        stage_half<2048>(Ag + t2, A0, w, l);
        phase_mid(); mfma_quad<0, 0>(acc, av, bvl); phase_end();

        // ph6: bv_hi | stage A0h1(2r+2) | Q1
        read_bv<2>(bvh, Bb1, br, lr, lg);
        stage_half<2048>(Ag + 262144 + t2, A0 + 16384, w, l);
        phase_mid(); mfma_quad<0, 2>(acc, av, bvh); phase_end();

        // ph7: av_hi | stage B1h0(2r+3) | Q2
        read_av<4>(av, Awm1, lr, lg);
        stage_half<4096>(Bg + t3, B1, w, l);
        phase_mid(); mfma_quad<4, 0>(acc, av, bvl); phase_end();

        // ph8: stage B1h1(2r+3) | vmcnt(4) | Q3
        stage_half<4096>(Bg + 524288 + t3, B1 + 16384, w, l);
        asm volatile("s_waitcnt vmcnt(4)" ::: "memory");
        phase_mid(); mfma_quad<4, 2>(acc, av, bvh); phase_end();
    }

    asm volatile("s_waitcnt vmcnt(0) lgkmcnt(0)" ::: "memory");
    __syncthreads();

    // ---- epilogue: z = acc + c, h = tanh(z), dot with W21/W22, reduce ----
    const float* cl = cbuf + (size_t)layer * 131072;
    const float* W2 = layer ? W22 : W21;
    float w2v[4];
    #pragma unroll
    for (int j = 0; j < 4; ++j) w2v[j] = W2[n0 + wn * 64 + j * 16 + lr];
    float* red = (float*)smem;   // [256][4]
    #pragma unroll
    for (int i = 0; i < 8; ++i) {
        #pragma unroll
        for (int q = 0; q < 4; ++q) {
            int wrow = wm * 128 + i * 16 + lg * 4 + q;   // 0..255 within M-tile
            int brow = wrow & 127;                        // b index (bx*256 ≡ 0 mod 128)
            float p = 0.f;
            #pragma unroll
            for (int j = 0; j < 4; ++j) {
                int col = n0 + wn * 64 + j * 16 + lr;
                float z = acc[i][j][q] + cl[(size_t)brow * 1024 + col];
                float e = __expf(2.f * z);
                p += (1.f - 2.f / (e + 1.f)) * w2v[j];
            }
            p += __shfl_xor(p, 1);
            p += __shfl_xor(p, 2);
            p += __shfl_xor(p, 4);
            p += __shfl_xor(p, 8);
            if (lr == 0) red[wrow * 4 + wn] = p;
        }
    }
    __syncthreads();
    if (tid < 256) {
        float v = red[tid * 4 + 0] + red[tid * 4 + 1] + red[tid * 4 + 2] + red[tid * 4 + 3];
        sbufp[(size_t)blockIdx.x * M_ROWS + (size_t)bx * 256 + tid] = v;
    }
}

// ---------------- Pass 6: softmax over s -> coef; also zero d_out ----------------
__device__ __forceinline__ float block_max(float v, float* lds) {
    #pragma unroll
    for (int m = 32; m; m >>= 1) v = fmaxf(v, __shfl_xor(v, m));
    if ((threadIdx.x & 63) == 0) lds[threadIdx.x >> 6] = v;
    __syncthreads();
    v = fmaxf(fmaxf(lds[0], lds[1]), fmaxf(lds[2], lds[3]));
    __syncthreads();
    return v;
}
__device__ __forceinline__ float block_sum(float v, float* lds) {
    #pragma unroll
    for (int m = 32; m; m >>= 1) v += __shfl_xor(v, m);
    if ((threadIdx.x & 63) == 0) lds[threadIdx.x >> 6] = v;
    __syncthreads();
    v = lds[0] + lds[1] + lds[2] + lds[3];
    __syncthreads();
    return v;
}

__global__ __launch_bounds__(256) void coef_kernel(const float* __restrict__ sbufp,
                                                   float* __restrict__ coef,
                                                   float* __restrict__ out) {
    __shared__ float lds[4];
    const int b = blockIdx.x, s = threadIdx.x;
    float v1 = 0.f, v2 = 0.f;
    #pragma unroll
    for (int nt = 0; nt < 4; ++nt) {
        v1 += sbufp[(size_t)nt * M_ROWS + (size_t)s * 128 + b];
        v2 += sbufp[(size_t)(4 + nt) * M_ROWS + (size_t)s * 128 + b];
    }
    float m1 = block_max(v1, lds);
    float e1 = expf(v1 - m1);
    float S1 = block_sum(e1, lds);
    float m2 = block_max(v2, lds);
    float e2 = expf(v2 - m2);
    float S2 = block_sum(e2, lds);
    coef[(size_t)s * 128 + b] = (e1 / S1 + e2 / S2) * (0.5f / (float)S_LEN);
    // zero d_out: block b owns row b (1024 floats = 256 float4)
    float4 z4; z4.x = z4.y = z4.z = z4.w = 0.f;
    ((float4*)out)[(size_t)b * 256 + s] = z4;
}

// ---------------- Pass 7: out[b][d] = sum_s coef[s][b] * seq[s][b][d] ----------------
__global__ __launch_bounds__(256) void final_kernel(const float* __restrict__ seq,
                                                    const float* __restrict__ coef,
                                                    float* __restrict__ out) {
    const int b = blockIdx.x, q = blockIdx.y;
    const int d0 = threadIdx.x * 4;
    float4 a; a.x = a.y = a.z = a.w = 0.f;
    for (int si = 0; si < 32; ++si) {
        int s = q * 32 + si;
        float cf = coef[(size_t)s * 128 + b];
        float4 v = *(const float4*)(seq + ((size_t)(s * 128 + b) * 1024 + d0));
        a.x += cf * v.x; a.y += cf * v.y; a.z += cf * v.z; a.w += cf * v.w;
    }
    float* o = out + (size_t)b * 1024 + d0;
    atomicAdd(o + 0, a.x);
    atomicAdd(o + 1, a.y);
    atomicAdd(o + 2, a.z);
    atomicAdd(o + 3, a.w);
}

extern "C" void kernel_launch(void* const* d_in, const int* in_sizes, int n_in,
                              void* d_out, int out_size, void* d_ws, size_t ws_size,
                              hipStream_t stream) {
    const float* feature1 = (const float*)d_in[0];   // [128,1024]
    const float* feature2 = (const float*)d_in[1];   // [128,1024]
    const float* seq      = (const float*)d_in[2];   // [256,128,1024]
    const float* W11      = (const float*)d_in[3];   // [2048,1024]
    const float* b11      = (const float*)d_in[4];
    const float* W12      = (const float*)d_in[5];
    const float* b12      = (const float*)d_in[6];
    const float* W21      = (const float*)d_in[7];   // [1024,1]
    const float* W22      = (const float*)d_in[9];
    float* out = (float*)d_out;

    char* ws = (char*)d_ws;
    unsigned short* Abf   = (unsigned short*)(ws + 0);                  // 67108864 B
    unsigned short* Wt    = (unsigned short*)(ws + 67108864);           //  8388608 B
    unsigned short* fbf   = (unsigned short*)(ws + 75497472);           //   524288 B
    float*          cbuf  = (float*)(ws + 76021760);                    //  1048576 B
    float*          sbufp = (float*)(ws + 77070336);                    //  1048576 B  [8][32768]
    float*          coef  = (float*)(ws + 78118912);                    //   131072 B

    convert_seq<<<2048, 256, 0, stream>>>(seq, Abf, (long)M_ROWS * 1024 / 4);
    convert_f<<<256, 256, 0, stream>>>(feature1, feature2, fbf);
    transpose_w<<<dim3(16, 32, 2), 256, 0, stream>>>(W11, W12, Wt);
    c_precompute<<<dim3(8, 2), 256, 0, stream>>>(fbf, Wt, b11, b12, cbuf);
    fused_main<<<dim3(8, 128), 512, 0, stream>>>(Abf, Wt, cbuf, W21, W22, sbufp);
    coef_kernel<<<128, 256, 0, stream>>>(sbufp, coef, out);
    final_kernel<<<dim3(128, 8), 256, 0, stream>>>(seq, coef, out);
}

// Round 5
// 258.698 us; speedup vs baseline: 1.3705x; 1.0497x over previous
//
#include <hip/hip_runtime.h>

// Problem constants
#define S_LEN 256
#define B_SZ  128
#define M_ROWS (S_LEN * B_SZ)          // 32768

typedef __attribute__((ext_vector_type(8))) short bf16x8;
typedef __attribute__((ext_vector_type(4))) float f32x4;

__device__ __forceinline__ unsigned short f2bf(float x) {
    unsigned u = __float_as_uint(x);
    unsigned r = (u + 0x7fffu + ((u >> 16) & 1u)) >> 16;   // RNE
    return (unsigned short)r;
}

__device__ __forceinline__ void gl_lds16(const void* g, void* l) {
    __builtin_amdgcn_global_load_lds(
        (const __attribute__((address_space(1))) unsigned int*)g,
        (__attribute__((address_space(3))) unsigned int*)l,
        16, 0, 0);
}

// ---------------- Pass 1: seq f32 -> bf16 ----------------
__global__ __launch_bounds__(256) void convert_seq(const float* __restrict__ in,
                                                   unsigned short* __restrict__ out,
                                                   long n4) {
    long i = (long)blockIdx.x * blockDim.x + threadIdx.x;
    long stride = (long)gridDim.x * blockDim.x;
    for (; i < n4; i += stride) {
        float4 v = ((const float4*)in)[i];
        ushort4 o;
        o.x = f2bf(v.x); o.y = f2bf(v.y); o.z = f2bf(v.z); o.w = f2bf(v.w);
        ((ushort4*)out)[i] = o;
    }
}

// ---------------- Pass 2: f1,f2 f32 -> bf16 (layer-major) ----------------
__global__ __launch_bounds__(256) void convert_f(const float* __restrict__ f1,
                                                 const float* __restrict__ f2,
                                                 unsigned short* __restrict__ out) {
    int g = blockIdx.x * 256 + threadIdx.x;            // 0..65535 float4 groups
    float4 v = (g < 32768) ? ((const float4*)f1)[g] : ((const float4*)f2)[g - 32768];
    ushort4 o;
    o.x = f2bf(v.x); o.y = f2bf(v.y); o.z = f2bf(v.z); o.w = f2bf(v.w);
    ((ushort4*)out)[g] = o;
}

// ---------------- Pass 3: W [2048][1024] f32 -> Wt [2][1024][2048] bf16 ----------------
__global__ __launch_bounds__(256) void transpose_w(const float* __restrict__ W11,
                                                   const float* __restrict__ W12,
                                                   unsigned short* __restrict__ Wt) {
    const int nt = blockIdx.x, kt = blockIdx.y, layer = blockIdx.z;
    const float* W = layer ? W12 : W11;
    __shared__ float T[64][65];
    const int c = threadIdx.x & 63, r4 = threadIdx.x >> 6;
    const int k0 = kt * 64, n0 = nt * 64;
    #pragma unroll
    for (int p = 0; p < 16; ++p) {
        int r = p * 4 + r4;
        T[r][c] = W[(size_t)(k0 + r) * 1024 + n0 + c];
    }
    __syncthreads();
    unsigned short* Wl = Wt + (size_t)layer * 1024 * 2048;
    #pragma unroll
    for (int p = 0; p < 16; ++p) {
        int n = p * 4 + r4;
        Wl[(size_t)(n0 + n) * 2048 + k0 + c] = f2bf(T[c][n]);
    }
}

// ---------------- Pass 4: c[layer][b][h] = f@W[1024:] + bias  (MFMA 128x128 tile) ----------------
__global__ __launch_bounds__(256) void c_precompute(const unsigned short* __restrict__ fbf, // [2][128][1024]
                                                    const unsigned short* __restrict__ Wt,  // [2][1024][2048]
                                                    const float* __restrict__ b11,
                                                    const float* __restrict__ b12,
                                                    float* __restrict__ cbuf) {            // [2][128][1024]
    __shared__ char smem[32768];
    unsigned short* ldsA = (unsigned short*)smem;            // [128][64]
    unsigned short* ldsB = (unsigned short*)(smem + 16384);  // [128][64]
    const int n0 = blockIdx.x * 128;
    const int layer = blockIdx.y;
    const int tid = threadIdx.x;
    const int w = tid >> 6, l = tid & 63;
    const int wm = w >> 1, wn = w & 1;
    const int lr = l & 15, lg = l >> 4;
    const unsigned short* Af = fbf + (size_t)layer * 128 * 1024;
    const unsigned short* Wl = Wt + (size_t)layer * 1024 * 2048;
    const float* bias = layer ? b12 : b11;

    f32x4 acc[4][4];
    #pragma unroll
    for (int i = 0; i < 4; ++i)
        #pragma unroll
        for (int j = 0; j < 4; ++j)
            #pragma unroll
            for (int e = 0; e < 4; ++e) acc[i][j][e] = 0.f;

    for (int kk = 0; kk < 1024; kk += 64) {
        __syncthreads();
        #pragma unroll
        for (int c = 0; c < 4; ++c) {
            int o = w * 4096 + c * 1024;
            int ob = o + l * 16;
            int row = ob >> 7, kb = ob & 127;
            gl_lds16((const char*)Af + ((size_t)row * 1024 + kk) * 2 + kb, (char*)ldsA + o);
            gl_lds16((const char*)Wl + ((size_t)(n0 + row) * 2048 + 1024 + kk) * 2 + kb, (char*)ldsB + o);
        }
        __syncthreads();
        #pragma unroll
        for (int ks = 0; ks < 2; ++ks) {
            bf16x8 av[4], bv[4];
            #pragma unroll
            for (int i = 0; i < 4; ++i) {
                av[i] = *(const bf16x8*)(ldsA + (wm * 64 + i * 16 + lr) * 64 + ks * 32 + lg * 8);
                bv[i] = *(const bf16x8*)(ldsB + (wn * 64 + i * 16 + lr) * 64 + ks * 32 + lg * 8);
            }
            #pragma unroll
            for (int i = 0; i < 4; ++i)
                #pragma unroll
                for (int j = 0; j < 4; ++j)
                    acc[i][j] = __builtin_amdgcn_mfma_f32_16x16x32_bf16(av[i], bv[j], acc[i][j], 0, 0, 0);
        }
    }
    float* cl = cbuf + (size_t)layer * 128 * 1024;
    #pragma unroll
    for (int i = 0; i < 4; ++i)
        #pragma unroll
        for (int j = 0; j < 4; ++j)
            #pragma unroll
            for (int q = 0; q < 4; ++q) {
                int rr = wm * 64 + i * 16 + lg * 4 + q;
                int hc = n0 + wn * 64 + j * 16 + lr;
                cl[(size_t)rr * 1024 + hc] = acc[i][j][q] + bias[hc];
            }
}

// ================= Pass 5: main fused GEMM, 256x256 tile, BK=32, 16 waves =================
// LDS: 4 buffers of 16 KB: A0 @0, B0 @16K, A1 @32K, B1 @48K  (64 KB total, dbuf).
// Tile layout [256 rows][32 K bf16] = [256][64 B].
// Swizzle (involution, 16B-chunk preserving): x ^= ((x>>7)&3)<<4
//   -> XOR row bits 1-2 into the 2-bit 16B-slot index. Combined with the row-parity
//   64B offset, 16 consecutive rows cover all 8 slot positions of the 128B bank
//   period twice => 2 lanes/bank = conflict-free (m136).
// global_load_lds: LINEAR dest (wave-uniform base, HW adds lane*16) + inverse-
// swizzled per-lane global source; ds_read applies the same XOR (both-sides rule).

__global__ __launch_bounds__(1024, 4) void fused_main(const unsigned short* __restrict__ Abf, // [32768][1024] bf16
                                                      const unsigned short* __restrict__ Wt,  // [2][1024][2048] bf16
                                                      const float* __restrict__ cbuf,         // [2][128][1024]
                                                      const float* __restrict__ W21,
                                                      const float* __restrict__ W22,
                                                      float* __restrict__ sbufp) {            // [8][32768]
    __shared__ char smem[65536];
    const int layer = blockIdx.x >> 2;
    const int nt    = blockIdx.x & 3;
    const int bx    = blockIdx.y;                  // M-tile (256 rows)
    const int tid = threadIdx.x;
    const int w = tid >> 6, l = tid & 63;
    const int wm = w >> 2, wn = w & 3;             // 4 M-quarters x 4 N-quarters
    const int lr = l & 15, lg = l >> 4;
    const int n0 = nt * 256;

    const char* Ag = (const char*)Abf + (size_t)bx * 256 * 2048;                          // row stride 2048 B
    const char* Bg = (const char*)(Wt + (size_t)layer * 1024 * 2048) + (size_t)n0 * 4096; // row stride 4096 B

    // staging: 32 KB per K-step, 1024 threads -> 2 gl_lds each (1 A + 1 B).
    // thread covers linear dest chunk dloc = w*1024 + l*16 of a 16 KB tile.
    const int dloc = w * 1024 + l * 16;
    const int gsw  = dloc ^ (((dloc >> 7) & 3) << 4);
    const char* srcA = Ag + (size_t)(gsw >> 6) * 2048 + (gsw & 63);
    const char* srcB = Bg + (size_t)(gsw >> 6) * 4096 + (gsw & 63);

    f32x4 acc[4][4];
    #pragma unroll
    for (int i = 0; i < 4; ++i)
        #pragma unroll
        for (int j = 0; j < 4; ++j)
            #pragma unroll
            for (int e = 0; e < 4; ++e) acc[i][j][e] = 0.f;

    // hoisted swizzled fragment offsets (invariant over t)
    int offA[4], offB[4];
    #pragma unroll
    for (int i = 0; i < 4; ++i) {
        int oa = (wm * 64 + i * 16 + lr) * 64 + lg * 16;
        offA[i] = oa ^ (((oa >> 7) & 3) << 4);
        int ob = (wn * 64 + i * 16 + lr) * 64 + lg * 16;
        offB[i] = ob ^ (((ob >> 7) & 3) << 4);
    }

    // prologue: stage K-step 0 into buf0
    gl_lds16(srcA, smem + w * 1024);
    gl_lds16(srcB, smem + 16384 + w * 1024);
    __syncthreads();

    for (int t = 0; t < 32; ++t) {
        const int cur = t & 1;
        if (t < 31) {
            char* db = smem + (cur ^ 1) * 32768 + w * 1024;
            gl_lds16(srcA + (size_t)(t + 1) * 64, db);
            gl_lds16(srcB + (size_t)(t + 1) * 64, db + 16384);
        }
        const char* Ab = smem + cur * 32768;
        const char* Bb = Ab + 16384;
        bf16x8 av[4], bv[4];
        #pragma unroll
        for (int i = 0; i < 4; ++i) av[i] = *(const bf16x8*)(Ab + offA[i]);
        #pragma unroll
        for (int j = 0; j < 4; ++j) bv[j] = *(const bf16x8*)(Bb + offB[j]);
        #pragma unroll
        for (int i = 0; i < 4; ++i)
            #pragma unroll
            for (int j = 0; j < 4; ++j)
                acc[i][j] = __builtin_amdgcn_mfma_f32_16x16x32_bf16(av[i], bv[j], acc[i][j], 0, 0, 0);
        __syncthreads();   // drains vmcnt(0): staged buf[cur^1] complete before next iter reads it
    }

    // ---- epilogue: z = acc + c, h = tanh(z), dot with W21/W22, reduce ----
    const float* cl = cbuf + (size_t)layer * 131072;
    const float* W2 = layer ? W22 : W21;
    float w2v[4];
    #pragma unroll
    for (int j = 0; j < 4; ++j) w2v[j] = W2[n0 + wn * 64 + j * 16 + lr];
    float* red = (float*)smem;   // [256][4]  (loop's final __syncthreads fences buffer reuse)
    #pragma unroll
    for (int i = 0; i < 4; ++i) {
        #pragma unroll
        for (int q = 0; q < 4; ++q) {
            int wrow = wm * 64 + i * 16 + lg * 4 + q;    // 0..255 within M-tile
            int brow = wrow & 127;                        // b index (bx*256 ≡ 0 mod 128)
            float p = 0.f;
            #pragma unroll
            for (int j = 0; j < 4; ++j) {
                int col = n0 + wn * 64 + j * 16 + lr;
                float z = acc[i][j][q] + cl[(size_t)brow * 1024 + col];
                float e = __expf(2.f * z);
                p += (1.f - 2.f / (e + 1.f)) * w2v[j];
            }
            p += __shfl_xor(p, 1);
            p += __shfl_xor(p, 2);
            p += __shfl_xor(p, 4);
            p += __shfl_xor(p, 8);
            if (lr == 0) red[wrow * 4 + wn] = p;
        }
    }
    __syncthreads();
    if (tid < 256) {
        float v = red[tid * 4 + 0] + red[tid * 4 + 1] + red[tid * 4 + 2] + red[tid * 4 + 3];
        sbufp[(size_t)blockIdx.x * M_ROWS + (size_t)bx * 256 + tid] = v;
    }
}

// ---------------- Pass 6: softmax over s -> coef; also zero d_out ----------------
__device__ __forceinline__ float block_max(float v, float* lds) {
    #pragma unroll
    for (int m = 32; m; m >>= 1) v = fmaxf(v, __shfl_xor(v, m));
    if ((threadIdx.x & 63) == 0) lds[threadIdx.x >> 6] = v;
    __syncthreads();
    v = fmaxf(fmaxf(lds[0], lds[1]), fmaxf(lds[2], lds[3]));
    __syncthreads();
    return v;
}
__device__ __forceinline__ float block_sum(float v, float* lds) {
    #pragma unroll
    for (int m = 32; m; m >>= 1) v += __shfl_xor(v, m);
    if ((threadIdx.x & 63) == 0) lds[threadIdx.x >> 6] = v;
    __syncthreads();
    v = lds[0] + lds[1] + lds[2] + lds[3];
    __syncthreads();
    return v;
}

__global__ __launch_bounds__(256) void coef_kernel(const float* __restrict__ sbufp,
                                                   float* __restrict__ coef,
                                                   float* __restrict__ out) {
    __shared__ float lds[4];
    const int b = blockIdx.x, s = threadIdx.x;
    float v1 = 0.f, v2 = 0.f;
    #pragma unroll
    for (int nt = 0; nt < 4; ++nt) {
        v1 += sbufp[(size_t)nt * M_ROWS + (size_t)s * 128 + b];
        v2 += sbufp[(size_t)(4 + nt) * M_ROWS + (size_t)s * 128 + b];
    }
    float m1 = block_max(v1, lds);
    float e1 = expf(v1 - m1);
    float S1 = block_sum(e1, lds);
    float m2 = block_max(v2, lds);
    float e2 = expf(v2 - m2);
    float S2 = block_sum(e2, lds);
    coef[(size_t)s * 128 + b] = (e1 / S1 + e2 / S2) * (0.5f / (float)S_LEN);
    // zero d_out: block b owns row b (1024 floats = 256 float4)
    float4 z4; z4.x = z4.y = z4.z = z4.w = 0.f;
    ((float4*)out)[(size_t)b * 256 + s] = z4;
}

// ---------------- Pass 7: out[b][d] = sum_s coef[s][b] * seq[s][b][d] ----------------
__global__ __launch_bounds__(256) void final_kernel(const float* __restrict__ seq,
                                                    const float* __restrict__ coef,
                                                    float* __restrict__ out) {
    const int b = blockIdx.x, q = blockIdx.y;
    const int d0 = threadIdx.x * 4;
    float4 a; a.x = a.y = a.z = a.w = 0.f;
    for (int si = 0; si < 32; ++si) {
        int s = q * 32 + si;
        float cf = coef[(size_t)s * 128 + b];
        float4 v = *(const float4*)(seq + ((size_t)(s * 128 + b) * 1024 + d0));
        a.x += cf * v.x; a.y += cf * v.y; a.z += cf * v.z; a.w += cf * v.w;
    }
    float* o = out + (size_t)b * 1024 + d0;
    atomicAdd(o + 0, a.x);
    atomicAdd(o + 1, a.y);
    atomicAdd(o + 2, a.z);
    atomicAdd(o + 3, a.w);
}

extern "C" void kernel_launch(void* const* d_in, const int* in_sizes, int n_in,
                              void* d_out, int out_size, void* d_ws, size_t ws_size,
                              hipStream_t stream) {
    const float* feature1 = (const float*)d_in[0];   // [128,1024]
    const float* feature2 = (const float*)d_in[1];   // [128,1024]
    const float* seq      = (const float*)d_in[2];   // [256,128,1024]
    const float* W11      = (const float*)d_in[3];   // [2048,1024]
    const float* b11      = (const float*)d_in[4];
    const float* W12      = (const float*)d_in[5];
    const float* b12      = (const float*)d_in[6];
    const float* W21      = (const float*)d_in[7];   // [1024,1]
    const float* W22      = (const float*)d_in[9];
    float* out = (float*)d_out;

    char* ws = (char*)d_ws;
    unsigned short* Abf   = (unsigned short*)(ws + 0);                  // 67108864 B
    unsigned short* Wt    = (unsigned short*)(ws + 67108864);           //  8388608 B
    unsigned short* fbf   = (unsigned short*)(ws + 75497472);           //   524288 B
    float*          cbuf  = (float*)(ws + 76021760);                    //  1048576 B
    float*          sbufp = (float*)(ws + 77070336);                    //  1048576 B  [8][32768]
    float*          coef  = (float*)(ws + 78118912);                    //   131072 B

    convert_seq<<<2048, 256, 0, stream>>>(seq, Abf, (long)M_ROWS * 1024 / 4);
    convert_f<<<256, 256, 0, stream>>>(feature1, feature2, fbf);
    transpose_w<<<dim3(16, 32, 2), 256, 0, stream>>>(W11, W12, Wt);
    c_precompute<<<dim3(8, 2), 256, 0, stream>>>(fbf, Wt, b11, b12, cbuf);
    fused_main<<<dim3(8, 128), 1024, 0, stream>>>(Abf, Wt, cbuf, W21, W22, sbufp);
    coef_kernel<<<128, 256, 0, stream>>>(sbufp, coef, out);
    final_kernel<<<dim3(128, 8), 256, 0, stream>>>(seq, coef, out);
}